// Round 17
// baseline (852.095 us; speedup 1.0000x reference)
//
#include <hip/hip_runtime.h>
#include <hip/hip_bf16.h>

typedef __attribute__((ext_vector_type(8))) short bf16x8;
typedef __attribute__((ext_vector_type(4))) float f32x4;

#define DEVI __device__ __forceinline__
#define MFMA __builtin_amdgcn_mfma_f32_16x16x32_bf16

DEVI short f2bf(float f) {
  union { float f; unsigned u; } v; v.f = f;
  unsigned r = v.u + 0x7FFFu + ((v.u >> 16) & 1u);
  return (short)(r >> 16);
}

DEVI float exp2a(float x) { float r; asm("v_exp_f32 %0, %1" : "=v"(r) : "v"(x)); return r; }

DEVI unsigned pk2(float lo, float hi) {
  union { __hip_bfloat162 h; unsigned u; } v;
  float2 f; f.x = lo; f.y = hi;
  v.h = __float22bfloat162_rn(f);
  return v.u;
}

union U8 { unsigned u[4]; bf16x8 v; };
DEVI bf16x8 mk8(unsigned a, unsigned b, unsigned c, unsigned d) {
  U8 x; x.u[0]=a; x.u[1]=b; x.u[2]=c; x.u[3]=d; return x.v;
}

// ---------------- prep: fragment-linear weight packs + biasT ----------------

__global__ __launch_bounds__(256) void prep_k(const float* __restrict__ wq,
                                              const float* __restrict__ wp,
                                              const float* __restrict__ btab,
                                              short* __restrict__ wqP,
                                              short* __restrict__ wpP,
                                              float* __restrict__ biasT) {
  int bid = blockIdx.x;
  if (bid < 4096) {
    int i = (bid < 3072 ? bid : bid - 3072) * 256 + threadIdx.x;
    int e = i & 7, lane = (i >> 3) & 63, kc = (i >> 9) & 15, cf = i >> 13;
    int k = kc * 32 + (lane >> 4) * 8 + e;
    int col = cf * 16 + (lane & 15);
    if (bid < 3072) wqP[i] = f2bf(wq[k * 1536 + col]);
    else            wpP[i] = f2bf(wp[k * 512 + col]);
  } else {
    int i = (bid - 4096) * 256 + threadIdx.x;   // 16*64*64
    int h = i >> 12, m = (i >> 6) & 63, n = i & 63;
    float v;
    if (m >= 49) {
      v = -1e30f;
    } else {
      int nn = n > 48 ? 48 : n;
      int ni = nn / 7, nj = nn - ni * 7;
      int mi = m / 7,  mj = m - mi * 7;
      int idx = (ni - mi + 6) * 13 + (nj - mj + 6);
      v = btab[idx * 16 + h] * 1.4426950408889634f;
    }
    biasT[i] = v;
  }
}

// ---------------- 256x256 bf16 GEMM: A reg-staged (fp32->bf16 fused when AF32), ----------
// B-frags direct from packed global. LDS now 64KB (K-loop A dbuf only) -> 2 blocks/CU.
// EPI0 epilogue bounces in TWO 128-row passes through the same 64KB.
// r17 delta vs r16: LDS 128KB -> 64KB (occupancy 1 -> 2 blocks/CU); K-loop unchanged.

template <int EPI, bool AF32>
__global__ __launch_bounds__(512)
void gemm256(const void* __restrict__ Ap, const short* __restrict__ wB,
             const float* __restrict__ bias, void* __restrict__ outp, int ctiles) {
  __shared__ short Ls[32768];   // 64 KB: K-loop [2][16384] A dbuf; epilogue [128][256] bounce

  const int nwg = gridDim.x;
  const int w = blockIdx.x;
  const int chunk = nwg >> 3;
  const int tid = (w & 7) * chunk + (w >> 3);    // XCD-contiguous remap (nwg%8==0)
  const int rt = tid / ctiles, ct = tid % ctiles;
  const long m0 = (long)rt * 256;
  const int n0 = ct * 256;

  const int t = threadIdx.x;          // 0..511
  const int lane = t & 63;
  const int wv = t >> 6;
  const int wr = wv >> 2;             // M half
  const int wc = wv & 3;              // N quarter
  const int l15 = lane & 15, g = lane >> 4, g4 = g * 4;

  // A staging: thread t -> LDS row t>>2 (+128), 16B slot t&3, global chunk swizzled
  const int gch = (t & 3) ^ ((t >> 3) & 3);
  const float* Agf = (const float*)Ap + (m0 + (t >> 2)) * 512 + gch * 8;
  const short* Agh = (const short*)Ap + (m0 + (t >> 2)) * 512 + gch * 8;

  const int cA = (g ^ ((l15 >> 1) & 3)) * 8;
  const int rowA = (wr * 128 + l15) * 32;

  // B frags: cf = ct*16 + wc*4 + nf ; addr = wB + (cf*16 + kc)*512 + lane*8
  const short* wBb = wB + ((long)(ct * 16 + wc * 4) << 13) + lane * 8;

  f32x4 acc[8][4] = {};
  bf16x8 af[8];
  bf16x8 bP[4][2];
  float4 ga[4][2];
  bf16x8 gb[4];

#define ISSUE_A(ktn)                                                          \
  if (AF32) {                                                                 \
    _Pragma("unroll")                                                         \
    for (int c = 0; c < 4; ++c) {                                             \
      const float* s_ = Agf + (c >> 1) * 65536 + (c & 1) * 32 + (ktn) * 64;   \
      ga[c][0] = *(const float4*)s_;                                          \
      ga[c][1] = *(const float4*)(s_ + 4);                                    \
    }                                                                         \
  } else {                                                                    \
    _Pragma("unroll")                                                         \
    for (int c = 0; c < 4; ++c)                                               \
      gb[c] = *(const bf16x8*)(Agh + (c >> 1) * 65536 + (c & 1) * 32 + (ktn) * 64); \
  }
#define WRITE_A(nb)                                                           \
  _Pragma("unroll")                                                           \
  for (int c = 0; c < 4; ++c) {                                               \
    short* d_ = (nb) + (c & 1) * 8192 + (c >> 1) * 4096 + t * 8;              \
    if (AF32) {                                                               \
      *(bf16x8*)d_ = mk8(pk2(ga[c][0].x, ga[c][0].y), pk2(ga[c][0].z, ga[c][0].w), \
                         pk2(ga[c][1].x, ga[c][1].y), pk2(ga[c][1].z, ga[c][1].w)); \
    } else {                                                                  \
      *(bf16x8*)d_ = gb[c];                                                   \
    }                                                                         \
  }
#define LOAD_BP(p, ktn)                                                       \
  bP[p][0] = *(const bf16x8*)(wBb + ((((((p) & 1) * 2 + 0) * 16 + ((ktn) * 2 + ((p) >> 1)))) << 9)); \
  bP[p][1] = *(const bf16x8*)(wBb + ((((((p) & 1) * 2 + 1) * 16 + ((ktn) * 2 + ((p) >> 1)))) << 9));
#define LOAD_AF(buf, kh)                                                      \
  _Pragma("unroll")                                                           \
  for (int mf = 0; mf < 8; ++mf)                                              \
    af[mf] = *(const bf16x8*)((buf) + (kh) * 8192 + rowA + mf * 512 + cA);
#define MFMA16(p)                                                             \
  __builtin_amdgcn_s_setprio(1);                                              \
  _Pragma("unroll")                                                           \
  for (int mf = 0; mf < 8; ++mf) {                                            \
    acc[mf][((p) & 1) * 2]     = MFMA(af[mf], bP[p][0], acc[mf][((p) & 1) * 2], 0, 0, 0);     \
    acc[mf][((p) & 1) * 2 + 1] = MFMA(af[mf], bP[p][1], acc[mf][((p) & 1) * 2 + 1], 0, 0, 0); \
  }                                                                           \
  __builtin_amdgcn_s_setprio(0);
#define BAR() asm volatile("s_barrier" ::: "memory")

  // prologue: stage kt0; issue kt1's A early; load kt0's B frags
  ISSUE_A(0);
  asm volatile("s_waitcnt vmcnt(0)" ::: "memory");
  WRITE_A(Ls);
  ISSUE_A(1);
  LOAD_BP(0, 0); LOAD_BP(1, 0); LOAD_BP(2, 0); LOAD_BP(3, 0);
  asm volatile("s_waitcnt lgkmcnt(0)" ::: "memory");
  BAR();

  for (int kt = 0; kt < 8; ++kt) {
    const short* buf = Ls + (kt & 1) * 16384;
    short* nb = Ls + ((kt & 1) ^ 1) * 16384;

    LOAD_AF(buf, 0);
    MFMA16(0);
    MFMA16(1);
    LOAD_AF(buf, 1);
    if (kt < 7) { LOAD_BP(0, kt + 1); LOAD_BP(1, kt + 1); }
    MFMA16(2);
    if (kt < 7) {
      asm volatile("s_waitcnt vmcnt(4)" ::: "memory");   // drain A(kt+1), keep bP01'
      WRITE_A(nb);                                       // A(kt+1) -> other buf
      if (kt < 6) ISSUE_A(kt + 2);                       // full K-tile of latency cover
    }
    MFMA16(3);
    if (kt < 7) { LOAD_BP(2, kt + 1); LOAD_BP(3, kt + 1); }
    asm volatile("s_waitcnt lgkmcnt(0)" ::: "memory");   // ds_writes retired
    BAR();                                               // sole barrier per K-tile
  }

  if (EPI == 0) {
    short* qkv = (short*)outp;
    const int cq = n0 >> 8;          // 0..5
    const int ii = cq >> 1;
#pragma unroll
    for (int p = 0; p < 2; ++p) {
      __syncthreads();               // Ls free (K-loop reads done / prev pass stores done)
      if (wr == p) {
#pragma unroll
        for (int mf = 0; mf < 8; ++mf)
#pragma unroll
          for (int r = 0; r < 4; ++r) {
            int lrow = mf * 16 + g4 + r;          // 0..127
#pragma unroll
            for (int nf = 0; nf < 4; ++nf) {
              int lcol = wc * 64 + nf * 16 + l15;
              Ls[lrow * 256 + lcol] = f2bf(acc[mf][nf][r] + bias[n0 + lcol]);
            }
          }
      }
      __syncthreads();
#pragma unroll
      for (int s = 0; s < 8; ++s) {
        int c = s * 512 + t;                      // 0..4095
        int row = c >> 5, sub = c & 31;
        int hl = sub >> 2, d0 = (sub & 3) * 8;
        int rg = (int)m0 + p * 128 + row;
        int b = rg / 49, n = rg - b * 49;
        int h = (cq & 1) * 8 + hl;
        long dst = (long)((b * 16 + h) * 3 + ii) * 1568 + n * 32 + d0;
        *(bf16x8*)(qkv + dst) = *(const bf16x8*)(Ls + row * 256 + hl * 32 + d0);
      }
    }
  } else {
    float* out = (float*)outp;
#pragma unroll
    for (int mf = 0; mf < 8; ++mf)
#pragma unroll
      for (int r = 0; r < 4; ++r) {
        long row = m0 + wr * 128 + mf * 16 + g4 + r;
#pragma unroll
        for (int nf = 0; nf < 4; ++nf) {
          int col = n0 + wc * 64 + nf * 16 + l15;
          out[row * 512 + col] = acc[mf][nf][r] + bias[col];
        }
      }
  }
#undef ISSUE_A
#undef WRITE_A
#undef LOAD_BP
#undef LOAD_AF
#undef MFMA16
#undef BAR
}

// ---------------- attention: swapped-QK^T, in-register softmax (r9-verified) ----------------

__global__ __launch_bounds__(256, 3)
void attn49(const short* __restrict__ qkvb, const float* __restrict__ biasT,
            short* __restrict__ ao) {
  __shared__ short Vl[4][2048];

  const int t = threadIdx.x, lane = t & 63, wv = t >> 6;
  const int l15 = lane & 15, g = lane >> 4, g4 = g * 4;
  const int b = blockIdx.x >> 2;
  const int h = (blockIdx.x & 3) * 4 + wv;

  const short* qb = qkvb + (long)(b * 16 + h) * 3 * 1568;
  const short* kb = qb + 1568;
  const short* vb = kb + 1568;
  short* Vs = Vl[wv];

#pragma unroll
  for (int it = 0; it < 4; ++it) {
    int c = it * 64 + lane; c = c > 195 ? 195 : c;
    *(bf16x8*)(Vs + c * 8) = *(const bf16x8*)(vb + c * 8);
  }

  bf16x8 qf[4], kf[4];
#pragma unroll
  for (int i = 0; i < 4; ++i) {
    int row = i * 16 + l15; row = row > 48 ? 48 : row;
    kf[i] = *(const bf16x8*)(kb + row * 32 + g * 8);
    qf[i] = *(const bf16x8*)(qb + row * 32 + g * 8);
  }

  f32x4 s[4][4] = {};
#pragma unroll
  for (int i = 0; i < 4; ++i)
#pragma unroll
    for (int j = 0; j < 4; ++j)
      s[i][j] = MFMA(kf[i], qf[j], s[i][j], 0, 0, 0);

  bf16x8 vf[2][2];
#pragma unroll
  for (int kt = 0; kt < 2; ++kt)
#pragma unroll
    for (int hi = 0; hi < 2; ++hi)
#pragma unroll
      for (int r = 0; r < 4; ++r) {
        int m = kt * 32 + hi * 16 + g4 + r;
        m = m > 48 ? 48 : m;
#pragma unroll
        for (int dt = 0; dt < 2; ++dt)
          vf[kt][dt][hi * 4 + r] = Vs[m * 32 + dt * 16 + l15];
      }

  const float* biasH = biasT + h * 4096;
  float sum[4] = {0.f, 0.f, 0.f, 0.f};
#pragma unroll
  for (int i = 0; i < 4; ++i)
#pragma unroll
    for (int r = 0; r < 4; ++r) {
      int m = i * 16 + g4 + r;
      const float* bp = biasH + m * 64 + l15;
#pragma unroll
      for (int j = 0; j < 4; ++j) {
        float p = exp2a(fmaf(s[i][j][r], 0.06375871f, bp[j * 16]));
        s[i][j][r] = p;
        sum[j] += p;
      }
    }
#pragma unroll
  for (int j = 0; j < 4; ++j) {
    sum[j] += __shfl_xor(sum[j], 16);
    sum[j] += __shfl_xor(sum[j], 32);
    sum[j] = 1.f / sum[j];
  }

  unsigned pk[4][4][2];
#pragma unroll
  for (int j = 0; j < 4; ++j)
#pragma unroll
    for (int i = 0; i < 4; ++i) {
      pk[j][i][0] = pk2(s[i][j][0] * sum[j], s[i][j][1] * sum[j]);
      pk[j][i][1] = pk2(s[i][j][2] * sum[j], s[i][j][3] * sum[j]);
    }

  f32x4 o[4][2] = {};
#pragma unroll
  for (int j = 0; j < 4; ++j) {
    bf16x8 a0 = mk8(pk[j][0][0], pk[j][0][1], pk[j][1][0], pk[j][1][1]);
    bf16x8 a1 = mk8(pk[j][2][0], pk[j][2][1], pk[j][3][0], pk[j][3][1]);
    o[j][0] = MFMA(a0, vf[0][0], o[j][0], 0, 0, 0);
    o[j][0] = MFMA(a1, vf[1][0], o[j][0], 0, 0, 0);
    o[j][1] = MFMA(a0, vf[0][1], o[j][1], 0, 0, 0);
    o[j][1] = MFMA(a1, vf[1][1], o[j][1], 0, 0, 0);
  }

#pragma unroll
  for (int j = 0; j < 4; ++j)
#pragma unroll
    for (int r = 0; r < 4; ++r) {
      int n = j * 16 + g4 + r;
      if (n < 49) {
        long off = ((long)b * 49 + n) * 512 + h * 32 + l15;
        ao[off]      = f2bf(o[j][0][r]);
        ao[off + 16] = f2bf(o[j][1][r]);
      }
    }
}

// ---------------- host ----------------

extern "C" void kernel_launch(void* const* d_in, const int* in_sizes, int n_in,
                              void* d_out, int out_size, void* d_ws, size_t ws_size,
                              hipStream_t stream) {
  (void)in_sizes; (void)n_in; (void)ws_size;
  const float* x      = (const float*)d_in[0];
  const float* w_qkv  = (const float*)d_in[1];
  const float* b_qkv  = (const float*)d_in[2];
  const float* w_proj = (const float*)d_in[3];
  const float* b_proj = (const float*)d_in[4];
  const float* btab   = (const float*)d_in[5];

  char* ws = (char*)d_ws;
  short* wqP = (short*)ws;                                   //   1,572,864 B
  short* wpP = (short*)(ws + 1572864L);                      //     524,288 B
  short* qkv = (short*)(ws + 2097152L);                      // 616,562,688 B
  short* ao  = (short*)(ws + 2097152L + 616562688L);         // 205,520,896 B
  // biasT in d_out tail: written by prep_k, read by attn49, fully overwritten by proj.
  float* biasT = (float*)d_out + (out_size - 65536);

  prep_k<<<4352, 256, 0, stream>>>(w_qkv, w_proj, btab, wqP, wpP, biasT);
  gemm256<0, true><<<4704, 512, 0, stream>>>(x, wqP, b_qkv, (void*)qkv, 6);
  attn49<<<16384, 256, 0, stream>>>(qkv, biasT, ao);
  gemm256<1, false><<<1568, 512, 0, stream>>>(ao, wpP, b_proj, d_out, 2);
}

// Round 18
// 833.415 us; speedup vs baseline: 1.0224x; 1.0224x over previous
//
#include <hip/hip_runtime.h>
#include <hip/hip_bf16.h>

typedef __attribute__((ext_vector_type(8))) short bf16x8;
typedef __attribute__((ext_vector_type(4))) float f32x4;

#define DEVI __device__ __forceinline__
#define MFMA __builtin_amdgcn_mfma_f32_16x16x32_bf16

DEVI short f2bf(float f) {
  union { float f; unsigned u; } v; v.f = f;
  unsigned r = v.u + 0x7FFFu + ((v.u >> 16) & 1u);
  return (short)(r >> 16);
}

DEVI float exp2a(float x) { float r; asm("v_exp_f32 %0, %1" : "=v"(r) : "v"(x)); return r; }

DEVI unsigned pk2(float lo, float hi) {
  union { __hip_bfloat162 h; unsigned u; } v;
  float2 f; f.x = lo; f.y = hi;
  v.h = __float22bfloat162_rn(f);
  return v.u;
}

union U8 { unsigned u[4]; bf16x8 v; };
DEVI bf16x8 mk8(unsigned a, unsigned b, unsigned c, unsigned d) {
  U8 x; x.u[0]=a; x.u[1]=b; x.u[2]=c; x.u[3]=d; return x.v;
}

// ---------------- prep: fragment-linear weight packs + biasT ----------------
// wqP[((cf*16+kc)*512 + lane*8 + e] = bf16(wq[k][col]); k = kc*32+(lane>>4)*8+e,
// col = cf*16+(lane&15).  wpP same from w_proj.  biasT as before.
__global__ __launch_bounds__(256) void prep_k(const float* __restrict__ wq,
                                              const float* __restrict__ wp,
                                              const float* __restrict__ btab,
                                              short* __restrict__ wqP,
                                              short* __restrict__ wpP,
                                              float* __restrict__ biasT) {
  int bid = blockIdx.x;
  if (bid < 4096) {
    int i = (bid < 3072 ? bid : bid - 3072) * 256 + threadIdx.x;
    int e = i & 7, lane = (i >> 3) & 63, kc = (i >> 9) & 15, cf = i >> 13;
    int k = kc * 32 + (lane >> 4) * 8 + e;
    int col = cf * 16 + (lane & 15);
    if (bid < 3072) wqP[i] = f2bf(wq[k * 1536 + col]);
    else            wpP[i] = f2bf(wp[k * 512 + col]);
  } else {
    int i = (bid - 4096) * 256 + threadIdx.x;   // 16*64*64
    int h = i >> 12, m = (i >> 6) & 63, n = i & 63;
    float v;
    if (m >= 49) {
      v = -1e30f;
    } else {
      int nn = n > 48 ? 48 : n;
      int ni = nn / 7, nj = nn - ni * 7;
      int mi = m / 7,  mj = m - mi * 7;
      int idx = (ni - mi + 6) * 13 + (nj - mj + 6);
      v = btab[idx * 16 + h] * 1.4426950408889634f;
    }
    biasT[i] = v;
  }
}

// ---------------- 256x256 bf16 GEMM: A reg-staged (fp32->bf16 fused when AF32), ----------
// B-frags direct from packed global (L1/L2-resident), LDS holds A only (64KB dbuf).
// A issued one full K-tile ahead (ISSUE_A(kt+2) right after WRITE_A consumes ga).
// NOTE: occupancy is register-bound (128 AGPR acc + ~124 VGPR -> 2 waves/SIMD);
// LDS size is NOT the limiter (r17 measured). Best measured: 833 us total.

template <int EPI, bool AF32>
__global__ __launch_bounds__(512)
void gemm256(const void* __restrict__ Ap, const short* __restrict__ wB,
             const float* __restrict__ bias, void* __restrict__ outp, int ctiles) {
  __shared__ short Ls[65536];   // K-loop: [2][16384] A dbuf; EPI0 epilogue: full 128KB

  const int nwg = gridDim.x;
  const int w = blockIdx.x;
  const int chunk = nwg >> 3;
  const int tid = (w & 7) * chunk + (w >> 3);    // XCD-contiguous remap (nwg%8==0)
  const int rt = tid / ctiles, ct = tid % ctiles;
  const long m0 = (long)rt * 256;
  const int n0 = ct * 256;

  const int t = threadIdx.x;          // 0..511
  const int lane = t & 63;
  const int wv = t >> 6;
  const int wr = wv >> 2;             // M half
  const int wc = wv & 3;              // N quarter
  const int l15 = lane & 15, g = lane >> 4, g4 = g * 4;

  // A staging: thread t -> LDS row t>>2 (+128), 16B slot t&3, global chunk swizzled
  const int gch = (t & 3) ^ ((t >> 3) & 3);
  const float* Agf = (const float*)Ap + (m0 + (t >> 2)) * 512 + gch * 8;
  const short* Agh = (const short*)Ap + (m0 + (t >> 2)) * 512 + gch * 8;

  const int cA = (g ^ ((l15 >> 1) & 3)) * 8;
  const int rowA = (wr * 128 + l15) * 32;

  // B frags: cf = ct*16 + wc*4 + nf ; addr = wB + (cf*16 + kc)*512 + lane*8
  const short* wBb = wB + ((long)(ct * 16 + wc * 4) << 13) + lane * 8;

  f32x4 acc[8][4] = {};
  bf16x8 af[8];
  bf16x8 bP[4][2];
  float4 ga[4][2];
  bf16x8 gb[4];

#define ISSUE_A(ktn)                                                          \
  if (AF32) {                                                                 \
    _Pragma("unroll")                                                         \
    for (int c = 0; c < 4; ++c) {                                             \
      const float* s_ = Agf + (c >> 1) * 65536 + (c & 1) * 32 + (ktn) * 64;   \
      ga[c][0] = *(const float4*)s_;                                          \
      ga[c][1] = *(const float4*)(s_ + 4);                                    \
    }                                                                         \
  } else {                                                                    \
    _Pragma("unroll")                                                         \
    for (int c = 0; c < 4; ++c)                                               \
      gb[c] = *(const bf16x8*)(Agh + (c >> 1) * 65536 + (c & 1) * 32 + (ktn) * 64); \
  }
#define WRITE_A(nb)                                                           \
  _Pragma("unroll")                                                           \
  for (int c = 0; c < 4; ++c) {                                               \
    short* d_ = (nb) + (c & 1) * 8192 + (c >> 1) * 4096 + t * 8;              \
    if (AF32) {                                                               \
      *(bf16x8*)d_ = mk8(pk2(ga[c][0].x, ga[c][0].y), pk2(ga[c][0].z, ga[c][0].w), \
                         pk2(ga[c][1].x, ga[c][1].y), pk2(ga[c][1].z, ga[c][1].w)); \
    } else {                                                                  \
      *(bf16x8*)d_ = gb[c];                                                   \
    }                                                                         \
  }
#define LOAD_BP(p, ktn)                                                       \
  bP[p][0] = *(const bf16x8*)(wBb + ((((((p) & 1) * 2 + 0) * 16 + ((ktn) * 2 + ((p) >> 1)))) << 9)); \
  bP[p][1] = *(const bf16x8*)(wBb + ((((((p) & 1) * 2 + 1) * 16 + ((ktn) * 2 + ((p) >> 1)))) << 9));
#define LOAD_AF(buf, kh)                                                      \
  _Pragma("unroll")                                                           \
  for (int mf = 0; mf < 8; ++mf)                                              \
    af[mf] = *(const bf16x8*)((buf) + (kh) * 8192 + rowA + mf * 512 + cA);
#define MFMA16(p)                                                             \
  __builtin_amdgcn_s_setprio(1);                                              \
  _Pragma("unroll")                                                           \
  for (int mf = 0; mf < 8; ++mf) {                                            \
    acc[mf][((p) & 1) * 2]     = MFMA(af[mf], bP[p][0], acc[mf][((p) & 1) * 2], 0, 0, 0);     \
    acc[mf][((p) & 1) * 2 + 1] = MFMA(af[mf], bP[p][1], acc[mf][((p) & 1) * 2 + 1], 0, 0, 0); \
  }                                                                           \
  __builtin_amdgcn_s_setprio(0);
#define BAR() asm volatile("s_barrier" ::: "memory")

  // prologue: stage kt0; issue kt1's A early; load kt0's B frags
  ISSUE_A(0);
  asm volatile("s_waitcnt vmcnt(0)" ::: "memory");
  WRITE_A(Ls);
  ISSUE_A(1);
  LOAD_BP(0, 0); LOAD_BP(1, 0); LOAD_BP(2, 0); LOAD_BP(3, 0);
  asm volatile("s_waitcnt lgkmcnt(0)" ::: "memory");
  BAR();

  for (int kt = 0; kt < 8; ++kt) {
    const short* buf = Ls + (kt & 1) * 16384;
    short* nb = Ls + ((kt & 1) ^ 1) * 16384;

    LOAD_AF(buf, 0);
    MFMA16(0);
    MFMA16(1);
    LOAD_AF(buf, 1);
    if (kt < 7) { LOAD_BP(0, kt + 1); LOAD_BP(1, kt + 1); }
    MFMA16(2);
    if (kt < 7) {
      asm volatile("s_waitcnt vmcnt(4)" ::: "memory");   // drain A(kt+1), keep bP01'
      WRITE_A(nb);                                       // A(kt+1) -> other buf
      if (kt < 6) ISSUE_A(kt + 2);                       // full K-tile of latency cover
    }
    MFMA16(3);
    if (kt < 7) { LOAD_BP(2, kt + 1); LOAD_BP(3, kt + 1); }
    asm volatile("s_waitcnt lgkmcnt(0)" ::: "memory");   // ds_writes retired
    BAR();                                               // sole barrier per K-tile
  }

  if (EPI == 0) {
    __syncthreads();   // Ls free for full 256x256 bounce tile
#pragma unroll
    for (int mf = 0; mf < 8; ++mf)
#pragma unroll
      for (int r = 0; r < 4; ++r) {
        int lrow = wr * 128 + mf * 16 + g4 + r;
#pragma unroll
        for (int nf = 0; nf < 4; ++nf) {
          int lcol = wc * 64 + nf * 16 + l15;
          Ls[lrow * 256 + lcol] = f2bf(acc[mf][nf][r] + bias[n0 + lcol]);
        }
      }
    __syncthreads();
    short* qkv = (short*)outp;
    const int cq = n0 >> 8;          // 0..5
    const int ii = cq >> 1;
#pragma unroll
    for (int s = 0; s < 16; ++s) {
      int c = s * 512 + t;
      int row = c >> 5, sub = c & 31;
      int hl = sub >> 2, d0 = (sub & 3) * 8;
      int rg = (int)m0 + row;
      int b = rg / 49, n = rg - b * 49;
      int h = (cq & 1) * 8 + hl;
      long dst = (long)((b * 16 + h) * 3 + ii) * 1568 + n * 32 + d0;
      *(bf16x8*)(qkv + dst) = *(const bf16x8*)(Ls + row * 256 + hl * 32 + d0);
    }
  } else {
    float* out = (float*)outp;
#pragma unroll
    for (int mf = 0; mf < 8; ++mf)
#pragma unroll
      for (int r = 0; r < 4; ++r) {
        long row = m0 + wr * 128 + mf * 16 + g4 + r;
#pragma unroll
        for (int nf = 0; nf < 4; ++nf) {
          int col = n0 + wc * 64 + nf * 16 + l15;
          out[row * 512 + col] = acc[mf][nf][r] + bias[col];
        }
      }
  }
#undef ISSUE_A
#undef WRITE_A
#undef LOAD_BP
#undef LOAD_AF
#undef MFMA16
#undef BAR
}

// ---------------- attention: swapped-QK^T, in-register softmax (r9-verified) ----------------

__global__ __launch_bounds__(256, 3)
void attn49(const short* __restrict__ qkvb, const float* __restrict__ biasT,
            short* __restrict__ ao) {
  __shared__ short Vl[4][2048];

  const int t = threadIdx.x, lane = t & 63, wv = t >> 6;
  const int l15 = lane & 15, g = lane >> 4, g4 = g * 4;
  const int b = blockIdx.x >> 2;
  const int h = (blockIdx.x & 3) * 4 + wv;

  const short* qb = qkvb + (long)(b * 16 + h) * 3 * 1568;
  const short* kb = qb + 1568;
  const short* vb = kb + 1568;
  short* Vs = Vl[wv];

#pragma unroll
  for (int it = 0; it < 4; ++it) {
    int c = it * 64 + lane; c = c > 195 ? 195 : c;
    *(bf16x8*)(Vs + c * 8) = *(const bf16x8*)(vb + c * 8);
  }

  bf16x8 qf[4], kf[4];
#pragma unroll
  for (int i = 0; i < 4; ++i) {
    int row = i * 16 + l15; row = row > 48 ? 48 : row;
    kf[i] = *(const bf16x8*)(kb + row * 32 + g * 8);
    qf[i] = *(const bf16x8*)(qb + row * 32 + g * 8);
  }

  f32x4 s[4][4] = {};
#pragma unroll
  for (int i = 0; i < 4; ++i)
#pragma unroll
    for (int j = 0; j < 4; ++j)
      s[i][j] = MFMA(kf[i], qf[j], s[i][j], 0, 0, 0);

  bf16x8 vf[2][2];
#pragma unroll
  for (int kt = 0; kt < 2; ++kt)
#pragma unroll
    for (int hi = 0; hi < 2; ++hi)
#pragma unroll
      for (int r = 0; r < 4; ++r) {
        int m = kt * 32 + hi * 16 + g4 + r;
        m = m > 48 ? 48 : m;
#pragma unroll
        for (int dt = 0; dt < 2; ++dt)
          vf[kt][dt][hi * 4 + r] = Vs[m * 32 + dt * 16 + l15];
      }

  const float* biasH = biasT + h * 4096;
  float sum[4] = {0.f, 0.f, 0.f, 0.f};
#pragma unroll
  for (int i = 0; i < 4; ++i)
#pragma unroll
    for (int r = 0; r < 4; ++r) {
      int m = i * 16 + g4 + r;
      const float* bp = biasH + m * 64 + l15;
#pragma unroll
      for (int j = 0; j < 4; ++j) {
        float p = exp2a(fmaf(s[i][j][r], 0.06375871f, bp[j * 16]));
        s[i][j][r] = p;
        sum[j] += p;
      }
    }
#pragma unroll
  for (int j = 0; j < 4; ++j) {
    sum[j] += __shfl_xor(sum[j], 16);
    sum[j] += __shfl_xor(sum[j], 32);
    sum[j] = 1.f / sum[j];
  }

  unsigned pk[4][4][2];
#pragma unroll
  for (int j = 0; j < 4; ++j)
#pragma unroll
    for (int i = 0; i < 4; ++i) {
      pk[j][i][0] = pk2(s[i][j][0] * sum[j], s[i][j][1] * sum[j]);
      pk[j][i][1] = pk2(s[i][j][2] * sum[j], s[i][j][3] * sum[j]);
    }

  f32x4 o[4][2] = {};
#pragma unroll
  for (int j = 0; j < 4; ++j) {
    bf16x8 a0 = mk8(pk[j][0][0], pk[j][0][1], pk[j][1][0], pk[j][1][1]);
    bf16x8 a1 = mk8(pk[j][2][0], pk[j][2][1], pk[j][3][0], pk[j][3][1]);
    o[j][0] = MFMA(a0, vf[0][0], o[j][0], 0, 0, 0);
    o[j][0] = MFMA(a1, vf[1][0], o[j][0], 0, 0, 0);
    o[j][1] = MFMA(a0, vf[0][1], o[j][1], 0, 0, 0);
    o[j][1] = MFMA(a1, vf[1][1], o[j][1], 0, 0, 0);
  }

#pragma unroll
  for (int j = 0; j < 4; ++j)
#pragma unroll
    for (int r = 0; r < 4; ++r) {
      int n = j * 16 + g4 + r;
      if (n < 49) {
        long off = ((long)b * 49 + n) * 512 + h * 32 + l15;
        ao[off]      = f2bf(o[j][0][r]);
        ao[off + 16] = f2bf(o[j][1][r]);
      }
    }
}

// ---------------- host ----------------

extern "C" void kernel_launch(void* const* d_in, const int* in_sizes, int n_in,
                              void* d_out, int out_size, void* d_ws, size_t ws_size,
                              hipStream_t stream) {
  (void)in_sizes; (void)n_in; (void)ws_size;
  const float* x      = (const float*)d_in[0];
  const float* w_qkv  = (const float*)d_in[1];
  const float* b_qkv  = (const float*)d_in[2];
  const float* w_proj = (const float*)d_in[3];
  const float* b_proj = (const float*)d_in[4];
  const float* btab   = (const float*)d_in[5];

  char* ws = (char*)d_ws;
  short* wqP = (short*)ws;                                   //   1,572,864 B
  short* wpP = (short*)(ws + 1572864L);                      //     524,288 B
  short* qkv = (short*)(ws + 2097152L);                      // 616,562,688 B
  short* ao  = (short*)(ws + 2097152L + 616562688L);         // 205,520,896 B
  // biasT in d_out tail: written by prep_k, read by attn49, fully overwritten by proj.
  float* biasT = (float*)d_out + (out_size - 65536);

  prep_k<<<4352, 256, 0, stream>>>(w_qkv, w_proj, btab, wqP, wpP, biasT);
  gemm256<0, true><<<4704, 512, 0, stream>>>(x, wqP, b_qkv, (void*)qkv, 6);
  attn49<<<16384, 256, 0, stream>>>(qkv, biasT, ao);
  gemm256<1, false><<<1568, 512, 0, stream>>>(ao, wpP, b_proj, d_out, 2);
}

// Round 19
// 831.179 us; speedup vs baseline: 1.0252x; 1.0027x over previous
//
#include <hip/hip_runtime.h>
#include <hip/hip_bf16.h>

typedef __attribute__((ext_vector_type(8))) short bf16x8;
typedef __attribute__((ext_vector_type(4))) float f32x4;

#define DEVI __device__ __forceinline__
#define MFMA __builtin_amdgcn_mfma_f32_16x16x32_bf16

DEVI short f2bf(float f) {
  union { float f; unsigned u; } v; v.f = f;
  unsigned r = v.u + 0x7FFFu + ((v.u >> 16) & 1u);
  return (short)(r >> 16);
}

DEVI float exp2a(float x) { float r; asm("v_exp_f32 %0, %1" : "=v"(r) : "v"(x)); return r; }

DEVI unsigned pk2(float lo, float hi) {
  union { __hip_bfloat162 h; unsigned u; } v;
  float2 f; f.x = lo; f.y = hi;
  v.h = __float22bfloat162_rn(f);
  return v.u;
}

union U8 { unsigned u[4]; bf16x8 v; };
DEVI bf16x8 mk8(unsigned a, unsigned b, unsigned c, unsigned d) {
  U8 x; x.u[0]=a; x.u[1]=b; x.u[2]=c; x.u[3]=d; return x.v;
}

// ---------------- prep: fragment-linear weight packs + biasT ----------------
// wqP[((cf*16+kc)*512 + lane*8 + e] = bf16(wq[k][col]); k = kc*32+(lane>>4)*8+e,
// col = cf*16+(lane&15).  wpP same from w_proj.  biasT as before.
__global__ __launch_bounds__(256) void prep_k(const float* __restrict__ wq,
                                              const float* __restrict__ wp,
                                              const float* __restrict__ btab,
                                              short* __restrict__ wqP,
                                              short* __restrict__ wpP,
                                              float* __restrict__ biasT) {
  int bid = blockIdx.x;
  if (bid < 4096) {
    int i = (bid < 3072 ? bid : bid - 3072) * 256 + threadIdx.x;
    int e = i & 7, lane = (i >> 3) & 63, kc = (i >> 9) & 15, cf = i >> 13;
    int k = kc * 32 + (lane >> 4) * 8 + e;
    int col = cf * 16 + (lane & 15);
    if (bid < 3072) wqP[i] = f2bf(wq[k * 1536 + col]);
    else            wpP[i] = f2bf(wp[k * 512 + col]);
  } else {
    int i = (bid - 4096) * 256 + threadIdx.x;   // 16*64*64
    int h = i >> 12, m = (i >> 6) & 63, n = i & 63;
    float v;
    if (m >= 49) {
      v = -1e30f;
    } else {
      int nn = n > 48 ? 48 : n;
      int ni = nn / 7, nj = nn - ni * 7;
      int mi = m / 7,  mj = m - mi * 7;
      int idx = (ni - mi + 6) * 13 + (nj - mj + 6);
      v = btab[idx * 16 + h] * 1.4426950408889634f;
    }
    biasT[i] = v;
  }
}

// ---------------- 256x256 bf16 GEMM: A reg-staged (fp32->bf16 fused when AF32), ----------
// B-frags direct from packed global (L1/L2-resident), LDS holds A only (64KB dbuf).
// A issued one full K-tile ahead. Occupancy is register-bound (128 AGPR acc +
// ~124 VGPR -> 2 waves/SIMD); LDS is NOT the limiter (r17 measured).

template <int EPI, bool AF32>
__global__ __launch_bounds__(512)
void gemm256(const void* __restrict__ Ap, const short* __restrict__ wB,
             const float* __restrict__ bias, void* __restrict__ outp, int ctiles) {
  __shared__ short Ls[65536];   // K-loop: [2][16384] A dbuf; EPI0 epilogue: full 128KB

  const int nwg = gridDim.x;
  const int w = blockIdx.x;
  const int chunk = nwg >> 3;
  const int tid = (w & 7) * chunk + (w >> 3);    // XCD-contiguous remap (nwg%8==0)
  const int rt = tid / ctiles, ct = tid % ctiles;
  const long m0 = (long)rt * 256;
  const int n0 = ct * 256;

  const int t = threadIdx.x;          // 0..511
  const int lane = t & 63;
  const int wv = t >> 6;
  const int wr = wv >> 2;             // M half
  const int wc = wv & 3;              // N quarter
  const int l15 = lane & 15, g = lane >> 4, g4 = g * 4;

  // A staging: thread t -> LDS row t>>2 (+128), 16B slot t&3, global chunk swizzled
  const int gch = (t & 3) ^ ((t >> 3) & 3);
  const float* Agf = (const float*)Ap + (m0 + (t >> 2)) * 512 + gch * 8;
  const short* Agh = (const short*)Ap + (m0 + (t >> 2)) * 512 + gch * 8;

  const int cA = (g ^ ((l15 >> 1) & 3)) * 8;
  const int rowA = (wr * 128 + l15) * 32;

  // B frags: cf = ct*16 + wc*4 + nf ; addr = wB + (cf*16 + kc)*512 + lane*8
  const short* wBb = wB + ((long)(ct * 16 + wc * 4) << 13) + lane * 8;

  f32x4 acc[8][4] = {};
  bf16x8 af[8];
  bf16x8 bP[4][2];
  float4 ga[4][2];
  bf16x8 gb[4];

#define ISSUE_A(ktn)                                                          \
  if (AF32) {                                                                 \
    _Pragma("unroll")                                                         \
    for (int c = 0; c < 4; ++c) {                                             \
      const float* s_ = Agf + (c >> 1) * 65536 + (c & 1) * 32 + (ktn) * 64;   \
      ga[c][0] = *(const float4*)s_;                                          \
      ga[c][1] = *(const float4*)(s_ + 4);                                    \
    }                                                                         \
  } else {                                                                    \
    _Pragma("unroll")                                                         \
    for (int c = 0; c < 4; ++c)                                               \
      gb[c] = *(const bf16x8*)(Agh + (c >> 1) * 65536 + (c & 1) * 32 + (ktn) * 64); \
  }
#define WRITE_A(nb)                                                           \
  _Pragma("unroll")                                                           \
  for (int c = 0; c < 4; ++c) {                                               \
    short* d_ = (nb) + (c & 1) * 8192 + (c >> 1) * 4096 + t * 8;              \
    if (AF32) {                                                               \
      *(bf16x8*)d_ = mk8(pk2(ga[c][0].x, ga[c][0].y), pk2(ga[c][0].z, ga[c][0].w), \
                         pk2(ga[c][1].x, ga[c][1].y), pk2(ga[c][1].z, ga[c][1].w)); \
    } else {                                                                  \
      *(bf16x8*)d_ = gb[c];                                                   \
    }                                                                         \
  }
#define LOAD_BP(p, ktn)                                                       \
  bP[p][0] = *(const bf16x8*)(wBb + ((((((p) & 1) * 2 + 0) * 16 + ((ktn) * 2 + ((p) >> 1)))) << 9)); \
  bP[p][1] = *(const bf16x8*)(wBb + ((((((p) & 1) * 2 + 1) * 16 + ((ktn) * 2 + ((p) >> 1)))) << 9));
#define LOAD_AF(buf, kh)                                                      \
  _Pragma("unroll")                                                           \
  for (int mf = 0; mf < 8; ++mf)                                              \
    af[mf] = *(const bf16x8*)((buf) + (kh) * 8192 + rowA + mf * 512 + cA);
#define MFMA16(p)                                                             \
  __builtin_amdgcn_s_setprio(1);                                              \
  _Pragma("unroll")                                                           \
  for (int mf = 0; mf < 8; ++mf) {                                            \
    acc[mf][((p) & 1) * 2]     = MFMA(af[mf], bP[p][0], acc[mf][((p) & 1) * 2], 0, 0, 0);     \
    acc[mf][((p) & 1) * 2 + 1] = MFMA(af[mf], bP[p][1], acc[mf][((p) & 1) * 2 + 1], 0, 0, 0); \
  }                                                                           \
  __builtin_amdgcn_s_setprio(0);
#define BAR() asm volatile("s_barrier" ::: "memory")

  // prologue: stage kt0; issue kt1's A early; load kt0's B frags
  ISSUE_A(0);
  asm volatile("s_waitcnt vmcnt(0)" ::: "memory");
  WRITE_A(Ls);
  ISSUE_A(1);
  LOAD_BP(0, 0); LOAD_BP(1, 0); LOAD_BP(2, 0); LOAD_BP(3, 0);
  asm volatile("s_waitcnt lgkmcnt(0)" ::: "memory");
  BAR();

  for (int kt = 0; kt < 8; ++kt) {
    const short* buf = Ls + (kt & 1) * 16384;
    short* nb = Ls + ((kt & 1) ^ 1) * 16384;

    LOAD_AF(buf, 0);
    MFMA16(0);
    MFMA16(1);
    LOAD_AF(buf, 1);
    if (kt < 7) { LOAD_BP(0, kt + 1); LOAD_BP(1, kt + 1); }
    MFMA16(2);
    if (kt < 7) {
      asm volatile("s_waitcnt vmcnt(4)" ::: "memory");   // drain A(kt+1), keep bP01'
      WRITE_A(nb);                                       // A(kt+1) -> other buf
      if (kt < 6) ISSUE_A(kt + 2);                       // full K-tile of latency cover
    }
    MFMA16(3);
    if (kt < 7) { LOAD_BP(2, kt + 1); LOAD_BP(3, kt + 1); }
    asm volatile("s_waitcnt lgkmcnt(0)" ::: "memory");   // ds_writes retired
    BAR();                                               // sole barrier per K-tile
  }

  if (EPI == 0) {
    __syncthreads();   // Ls free for full 256x256 bounce tile
#pragma unroll
    for (int mf = 0; mf < 8; ++mf)
#pragma unroll
      for (int r = 0; r < 4; ++r) {
        int lrow = wr * 128 + mf * 16 + g4 + r;
#pragma unroll
        for (int nf = 0; nf < 4; ++nf) {
          int lcol = wc * 64 + nf * 16 + l15;
          Ls[lrow * 256 + lcol] = f2bf(acc[mf][nf][r] + bias[n0 + lcol]);
        }
      }
    __syncthreads();
    short* qkv = (short*)outp;
    const int cq = n0 >> 8;          // 0..5
    const int ii = cq >> 1;
#pragma unroll
    for (int s = 0; s < 16; ++s) {
      int c = s * 512 + t;
      int row = c >> 5, sub = c & 31;
      int hl = sub >> 2, d0 = (sub & 3) * 8;
      int rg = (int)m0 + row;
      int b = rg / 49, n = rg - b * 49;
      int h = (cq & 1) * 8 + hl;
      long dst = (long)((b * 16 + h) * 3 + ii) * 1568 + n * 32 + d0;
      *(bf16x8*)(qkv + dst) = *(const bf16x8*)(Ls + row * 256 + hl * 32 + d0);
    }
  } else {
    float* out = (float*)outp;
#pragma unroll
    for (int mf = 0; mf < 8; ++mf)
#pragma unroll
      for (int r = 0; r < 4; ++r) {
        long row = m0 + wr * 128 + mf * 16 + g4 + r;
#pragma unroll
        for (int nf = 0; nf < 4; ++nf) {
          int col = n0 + wc * 64 + nf * 16 + l15;
          out[row * 512 + col] = acc[mf][nf][r] + bias[col];
        }
      }
  }
#undef ISSUE_A
#undef WRITE_A
#undef LOAD_BP
#undef LOAD_AF
#undef MFMA16
#undef BAR
}

// ---------------- attention: swapped-QK^T, in-register softmax ----------------
// r19 delta: __launch_bounds__(256,3) -> (256,4): 4 blocks/CU target (reg cap 128,
// kernel fits; spill-safe worst case). LDS 16KB/block allows it.

__global__ __launch_bounds__(256, 4)
void attn49(const short* __restrict__ qkvb, const float* __restrict__ biasT,
            short* __restrict__ ao) {
  __shared__ short Vl[4][2048];

  const int t = threadIdx.x, lane = t & 63, wv = t >> 6;
  const int l15 = lane & 15, g = lane >> 4, g4 = g * 4;
  const int b = blockIdx.x >> 2;
  const int h = (blockIdx.x & 3) * 4 + wv;

  const short* qb = qkvb + (long)(b * 16 + h) * 3 * 1568;
  const short* kb = qb + 1568;
  const short* vb = kb + 1568;
  short* Vs = Vl[wv];

#pragma unroll
  for (int it = 0; it < 4; ++it) {
    int c = it * 64 + lane; c = c > 195 ? 195 : c;
    *(bf16x8*)(Vs + c * 8) = *(const bf16x8*)(vb + c * 8);
  }

  bf16x8 qf[4], kf[4];
#pragma unroll
  for (int i = 0; i < 4; ++i) {
    int row = i * 16 + l15; row = row > 48 ? 48 : row;
    kf[i] = *(const bf16x8*)(kb + row * 32 + g * 8);
    qf[i] = *(const bf16x8*)(qb + row * 32 + g * 8);
  }

  f32x4 s[4][4] = {};
#pragma unroll
  for (int i = 0; i < 4; ++i)
#pragma unroll
    for (int j = 0; j < 4; ++j)
      s[i][j] = MFMA(kf[i], qf[j], s[i][j], 0, 0, 0);

  bf16x8 vf[2][2];
#pragma unroll
  for (int kt = 0; kt < 2; ++kt)
#pragma unroll
    for (int hi = 0; hi < 2; ++hi)
#pragma unroll
      for (int r = 0; r < 4; ++r) {
        int m = kt * 32 + hi * 16 + g4 + r;
        m = m > 48 ? 48 : m;
#pragma unroll
        for (int dt = 0; dt < 2; ++dt)
          vf[kt][dt][hi * 4 + r] = Vs[m * 32 + dt * 16 + l15];
      }

  const float* biasH = biasT + h * 4096;
  float sum[4] = {0.f, 0.f, 0.f, 0.f};
#pragma unroll
  for (int i = 0; i < 4; ++i)
#pragma unroll
    for (int r = 0; r < 4; ++r) {
      int m = i * 16 + g4 + r;
      const float* bp = biasH + m * 64 + l15;
#pragma unroll
      for (int j = 0; j < 4; ++j) {
        float p = exp2a(fmaf(s[i][j][r], 0.06375871f, bp[j * 16]));
        s[i][j][r] = p;
        sum[j] += p;
      }
    }
#pragma unroll
  for (int j = 0; j < 4; ++j) {
    sum[j] += __shfl_xor(sum[j], 16);
    sum[j] += __shfl_xor(sum[j], 32);
    sum[j] = 1.f / sum[j];
  }

  unsigned pk[4][4][2];
#pragma unroll
  for (int j = 0; j < 4; ++j)
#pragma unroll
    for (int i = 0; i < 4; ++i) {
      pk[j][i][0] = pk2(s[i][j][0] * sum[j], s[i][j][1] * sum[j]);
      pk[j][i][1] = pk2(s[i][j][2] * sum[j], s[i][j][3] * sum[j]);
    }

  f32x4 o[4][2] = {};
#pragma unroll
  for (int j = 0; j < 4; ++j) {
    bf16x8 a0 = mk8(pk[j][0][0], pk[j][0][1], pk[j][1][0], pk[j][1][1]);
    bf16x8 a1 = mk8(pk[j][2][0], pk[j][2][1], pk[j][3][0], pk[j][3][1]);
    o[j][0] = MFMA(a0, vf[0][0], o[j][0], 0, 0, 0);
    o[j][0] = MFMA(a1, vf[1][0], o[j][0], 0, 0, 0);
    o[j][1] = MFMA(a0, vf[0][1], o[j][1], 0, 0, 0);
    o[j][1] = MFMA(a1, vf[1][1], o[j][1], 0, 0, 0);
  }

#pragma unroll
  for (int j = 0; j < 4; ++j)
#pragma unroll
    for (int r = 0; r < 4; ++r) {
      int n = j * 16 + g4 + r;
      if (n < 49) {
        long off = ((long)b * 49 + n) * 512 + h * 32 + l15;
        ao[off]      = f2bf(o[j][0][r]);
        ao[off + 16] = f2bf(o[j][1][r]);
      }
    }
}

// ---------------- host ----------------

extern "C" void kernel_launch(void* const* d_in, const int* in_sizes, int n_in,
                              void* d_out, int out_size, void* d_ws, size_t ws_size,
                              hipStream_t stream) {
  (void)in_sizes; (void)n_in; (void)ws_size;
  const float* x      = (const float*)d_in[0];
  const float* w_qkv  = (const float*)d_in[1];
  const float* b_qkv  = (const float*)d_in[2];
  const float* w_proj = (const float*)d_in[3];
  const float* b_proj = (const float*)d_in[4];
  const float* btab   = (const float*)d_in[5];

  char* ws = (char*)d_ws;
  short* wqP = (short*)ws;                                   //   1,572,864 B
  short* wpP = (short*)(ws + 1572864L);                      //     524,288 B
  short* qkv = (short*)(ws + 2097152L);                      // 616,562,688 B
  short* ao  = (short*)(ws + 2097152L + 616562688L);         // 205,520,896 B
  // biasT in d_out tail: written by prep_k, read by attn49, fully overwritten by proj.
  float* biasT = (float*)d_out + (out_size - 65536);

  prep_k<<<4352, 256, 0, stream>>>(w_qkv, w_proj, btab, wqP, wpP, biasT);
  gemm256<0, true><<<4704, 512, 0, stream>>>(x, wqP, b_qkv, (void*)qkv, 6);
  attn49<<<16384, 256, 0, stream>>>(qkv, biasT, ao);
  gemm256<1, false><<<1568, 512, 0, stream>>>(ao, wpP, b_proj, d_out, 2);
}

// Round 20
// 830.179 us; speedup vs baseline: 1.0264x; 1.0012x over previous
//
#include <hip/hip_runtime.h>
#include <hip/hip_bf16.h>

typedef __attribute__((ext_vector_type(8))) short bf16x8;
typedef __attribute__((ext_vector_type(4))) float f32x4;

#define DEVI __device__ __forceinline__
#define MFMA __builtin_amdgcn_mfma_f32_16x16x32_bf16

DEVI short f2bf(float f) {
  union { float f; unsigned u; } v; v.f = f;
  unsigned r = v.u + 0x7FFFu + ((v.u >> 16) & 1u);
  return (short)(r >> 16);
}

DEVI float exp2a(float x) { float r; asm("v_exp_f32 %0, %1" : "=v"(r) : "v"(x)); return r; }

DEVI unsigned pk2(float lo, float hi) {
  union { __hip_bfloat162 h; unsigned u; } v;
  float2 f; f.x = lo; f.y = hi;
  v.h = __float22bfloat162_rn(f);
  return v.u;
}

union U8 { unsigned u[4]; bf16x8 v; };
DEVI bf16x8 mk8(unsigned a, unsigned b, unsigned c, unsigned d) {
  U8 x; x.u[0]=a; x.u[1]=b; x.u[2]=c; x.u[3]=d; return x.v;
}

// ---------------- prep: fragment-linear weight packs + biasT ----------------
// wqP[((cf*16+kc)*512 + lane*8 + e] = bf16(wq[k][col]); k = kc*32+(lane>>4)*8+e,
// col = cf*16+(lane&15).  wpP same from w_proj.  biasT = bias*log2e, -1e30 pad.
__global__ __launch_bounds__(256) void prep_k(const float* __restrict__ wq,
                                              const float* __restrict__ wp,
                                              const float* __restrict__ btab,
                                              short* __restrict__ wqP,
                                              short* __restrict__ wpP,
                                              float* __restrict__ biasT) {
  int bid = blockIdx.x;
  if (bid < 4096) {
    int i = (bid < 3072 ? bid : bid - 3072) * 256 + threadIdx.x;
    int e = i & 7, lane = (i >> 3) & 63, kc = (i >> 9) & 15, cf = i >> 13;
    int k = kc * 32 + (lane >> 4) * 8 + e;
    int col = cf * 16 + (lane & 15);
    if (bid < 3072) wqP[i] = f2bf(wq[k * 1536 + col]);
    else            wpP[i] = f2bf(wp[k * 512 + col]);
  } else {
    int i = (bid - 4096) * 256 + threadIdx.x;   // 16*64*64
    int h = i >> 12, m = (i >> 6) & 63, n = i & 63;
    float v;
    if (m >= 49) {
      v = -1e30f;
    } else {
      int nn = n > 48 ? 48 : n;
      int ni = nn / 7, nj = nn - ni * 7;
      int mi = m / 7,  mj = m - mi * 7;
      int idx = (ni - mi + 6) * 13 + (nj - mj + 6);
      v = btab[idx * 16 + h] * 1.4426950408889634f;
    }
    biasT[i] = v;
  }
}

// ---------------- 256x256 bf16 GEMM: A reg-staged (fp32->bf16 fused when AF32), ----------
// B-frags direct from packed global (L1/L2-resident), LDS holds A only (64KB dbuf).
// A issued one full K-tile ahead. Occupancy is register-bound (128 AGPR acc +
// ~124 VGPR -> 2 waves/SIMD); LDS is NOT the limiter (r17 measured).

template <int EPI, bool AF32>
__global__ __launch_bounds__(512)
void gemm256(const void* __restrict__ Ap, const short* __restrict__ wB,
             const float* __restrict__ bias, void* __restrict__ outp, int ctiles) {
  __shared__ short Ls[65536];   // K-loop: [2][16384] A dbuf; EPI0 epilogue: full 128KB

  const int nwg = gridDim.x;
  const int w = blockIdx.x;
  const int chunk = nwg >> 3;
  const int tid = (w & 7) * chunk + (w >> 3);    // XCD-contiguous remap (nwg%8==0)
  const int rt = tid / ctiles, ct = tid % ctiles;
  const long m0 = (long)rt * 256;
  const int n0 = ct * 256;

  const int t = threadIdx.x;          // 0..511
  const int lane = t & 63;
  const int wv = t >> 6;
  const int wr = wv >> 2;             // M half
  const int wc = wv & 3;              // N quarter
  const int l15 = lane & 15, g = lane >> 4, g4 = g * 4;

  // A staging: thread t -> LDS row t>>2 (+128), 16B slot t&3, global chunk swizzled
  const int gch = (t & 3) ^ ((t >> 3) & 3);
  const float* Agf = (const float*)Ap + (m0 + (t >> 2)) * 512 + gch * 8;
  const short* Agh = (const short*)Ap + (m0 + (t >> 2)) * 512 + gch * 8;

  const int cA = (g ^ ((l15 >> 1) & 3)) * 8;
  const int rowA = (wr * 128 + l15) * 32;

  // B frags: cf = ct*16 + wc*4 + nf ; addr = wB + (cf*16 + kc)*512 + lane*8
  const short* wBb = wB + ((long)(ct * 16 + wc * 4) << 13) + lane * 8;

  f32x4 acc[8][4] = {};
  bf16x8 af[8];
  bf16x8 bP[4][2];
  float4 ga[4][2];
  bf16x8 gb[4];

#define ISSUE_A(ktn)                                                          \
  if (AF32) {                                                                 \
    _Pragma("unroll")                                                         \
    for (int c = 0; c < 4; ++c) {                                             \
      const float* s_ = Agf + (c >> 1) * 65536 + (c & 1) * 32 + (ktn) * 64;   \
      ga[c][0] = *(const float4*)s_;                                          \
      ga[c][1] = *(const float4*)(s_ + 4);                                    \
    }                                                                         \
  } else {                                                                    \
    _Pragma("unroll")                                                         \
    for (int c = 0; c < 4; ++c)                                               \
      gb[c] = *(const bf16x8*)(Agh + (c >> 1) * 65536 + (c & 1) * 32 + (ktn) * 64); \
  }
#define WRITE_A(nb)                                                           \
  _Pragma("unroll")                                                           \
  for (int c = 0; c < 4; ++c) {                                               \
    short* d_ = (nb) + (c & 1) * 8192 + (c >> 1) * 4096 + t * 8;              \
    if (AF32) {                                                               \
      *(bf16x8*)d_ = mk8(pk2(ga[c][0].x, ga[c][0].y), pk2(ga[c][0].z, ga[c][0].w), \
                         pk2(ga[c][1].x, ga[c][1].y), pk2(ga[c][1].z, ga[c][1].w)); \
    } else {                                                                  \
      *(bf16x8*)d_ = gb[c];                                                   \
    }                                                                         \
  }
#define LOAD_BP(p, ktn)                                                       \
  bP[p][0] = *(const bf16x8*)(wBb + ((((((p) & 1) * 2 + 0) * 16 + ((ktn) * 2 + ((p) >> 1)))) << 9)); \
  bP[p][1] = *(const bf16x8*)(wBb + ((((((p) & 1) * 2 + 1) * 16 + ((ktn) * 2 + ((p) >> 1)))) << 9));
#define LOAD_AF(buf, kh)                                                      \
  _Pragma("unroll")                                                           \
  for (int mf = 0; mf < 8; ++mf)                                              \
    af[mf] = *(const bf16x8*)((buf) + (kh) * 8192 + rowA + mf * 512 + cA);
#define MFMA16(p)                                                             \
  __builtin_amdgcn_s_setprio(1);                                              \
  _Pragma("unroll")                                                           \
  for (int mf = 0; mf < 8; ++mf) {                                            \
    acc[mf][((p) & 1) * 2]     = MFMA(af[mf], bP[p][0], acc[mf][((p) & 1) * 2], 0, 0, 0);     \
    acc[mf][((p) & 1) * 2 + 1] = MFMA(af[mf], bP[p][1], acc[mf][((p) & 1) * 2 + 1], 0, 0, 0); \
  }                                                                           \
  __builtin_amdgcn_s_setprio(0);
#define BAR() asm volatile("s_barrier" ::: "memory")

  // prologue: stage kt0; issue kt1's A early; load kt0's B frags
  ISSUE_A(0);
  asm volatile("s_waitcnt vmcnt(0)" ::: "memory");
  WRITE_A(Ls);
  ISSUE_A(1);
  LOAD_BP(0, 0); LOAD_BP(1, 0); LOAD_BP(2, 0); LOAD_BP(3, 0);
  asm volatile("s_waitcnt lgkmcnt(0)" ::: "memory");
  BAR();

  for (int kt = 0; kt < 8; ++kt) {
    const short* buf = Ls + (kt & 1) * 16384;
    short* nb = Ls + ((kt & 1) ^ 1) * 16384;

    LOAD_AF(buf, 0);
    MFMA16(0);
    MFMA16(1);
    LOAD_AF(buf, 1);
    if (kt < 7) { LOAD_BP(0, kt + 1); LOAD_BP(1, kt + 1); }
    MFMA16(2);
    if (kt < 7) {
      asm volatile("s_waitcnt vmcnt(4)" ::: "memory");   // drain A(kt+1), keep bP01'
      WRITE_A(nb);                                       // A(kt+1) -> other buf
      if (kt < 6) ISSUE_A(kt + 2);                       // full K-tile of latency cover
    }
    MFMA16(3);
    if (kt < 7) { LOAD_BP(2, kt + 1); LOAD_BP(3, kt + 1); }
    asm volatile("s_waitcnt lgkmcnt(0)" ::: "memory");   // ds_writes retired
    BAR();                                               // sole barrier per K-tile
  }

  if (EPI == 0) {
    __syncthreads();   // Ls free for full 256x256 bounce tile
#pragma unroll
    for (int mf = 0; mf < 8; ++mf)
#pragma unroll
      for (int r = 0; r < 4; ++r) {
        int lrow = wr * 128 + mf * 16 + g4 + r;
#pragma unroll
        for (int nf = 0; nf < 4; ++nf) {
          int lcol = wc * 64 + nf * 16 + l15;
          Ls[lrow * 256 + lcol] = f2bf(acc[mf][nf][r] + bias[n0 + lcol]);
        }
      }
    __syncthreads();
    short* qkv = (short*)outp;
    const int cq = n0 >> 8;          // 0..5
    const int ii = cq >> 1;
#pragma unroll
    for (int s = 0; s < 16; ++s) {
      int c = s * 512 + t;
      int row = c >> 5, sub = c & 31;
      int hl = sub >> 2, d0 = (sub & 3) * 8;
      int rg = (int)m0 + row;
      int b = rg / 49, n = rg - b * 49;
      int h = (cq & 1) * 8 + hl;
      long dst = (long)((b * 16 + h) * 3 + ii) * 1568 + n * 32 + d0;
      *(bf16x8*)(qkv + dst) = *(const bf16x8*)(Ls + row * 256 + hl * 32 + d0);
    }
  } else {
    float* out = (float*)outp;
#pragma unroll
    for (int mf = 0; mf < 8; ++mf)
#pragma unroll
      for (int r = 0; r < 4; ++r) {
        long row = m0 + wr * 128 + mf * 16 + g4 + r;
#pragma unroll
        for (int nf = 0; nf < 4; ++nf) {
          int col = n0 + wc * 64 + nf * 16 + l15;
          out[row * 512 + col] = acc[mf][nf][r] + bias[col];
        }
      }
  }
#undef ISSUE_A
#undef WRITE_A
#undef LOAD_BP
#undef LOAD_AF
#undef MFMA16
#undef BAR
}

// ---------------- attention: swapped-QK^T, in-register softmax ----------------

__global__ __launch_bounds__(256, 4)
void attn49(const short* __restrict__ qkvb, const float* __restrict__ biasT,
            short* __restrict__ ao) {
  __shared__ short Vl[4][2048];

  const int t = threadIdx.x, lane = t & 63, wv = t >> 6;
  const int l15 = lane & 15, g = lane >> 4, g4 = g * 4;
  const int b = blockIdx.x >> 2;
  const int h = (blockIdx.x & 3) * 4 + wv;

  const short* qb = qkvb + (long)(b * 16 + h) * 3 * 1568;
  const short* kb = qb + 1568;
  const short* vb = kb + 1568;
  short* Vs = Vl[wv];

#pragma unroll
  for (int it = 0; it < 4; ++it) {
    int c = it * 64 + lane; c = c > 195 ? 195 : c;
    *(bf16x8*)(Vs + c * 8) = *(const bf16x8*)(vb + c * 8);
  }

  bf16x8 qf[4], kf[4];
#pragma unroll
  for (int i = 0; i < 4; ++i) {
    int row = i * 16 + l15; row = row > 48 ? 48 : row;
    kf[i] = *(const bf16x8*)(kb + row * 32 + g * 8);
    qf[i] = *(const bf16x8*)(qb + row * 32 + g * 8);
  }

  f32x4 s[4][4] = {};
#pragma unroll
  for (int i = 0; i < 4; ++i)
#pragma unroll
    for (int j = 0; j < 4; ++j)
      s[i][j] = MFMA(kf[i], qf[j], s[i][j], 0, 0, 0);

  bf16x8 vf[2][2];
#pragma unroll
  for (int kt = 0; kt < 2; ++kt)
#pragma unroll
    for (int hi = 0; hi < 2; ++hi)
#pragma unroll
      for (int r = 0; r < 4; ++r) {
        int m = kt * 32 + hi * 16 + g4 + r;
        m = m > 48 ? 48 : m;
#pragma unroll
        for (int dt = 0; dt < 2; ++dt)
          vf[kt][dt][hi * 4 + r] = Vs[m * 32 + dt * 16 + l15];
      }

  const float* biasH = biasT + h * 4096;
  float sum[4] = {0.f, 0.f, 0.f, 0.f};
#pragma unroll
  for (int i = 0; i < 4; ++i)
#pragma unroll
    for (int r = 0; r < 4; ++r) {
      int m = i * 16 + g4 + r;
      const float* bp = biasH + m * 64 + l15;
#pragma unroll
      for (int j = 0; j < 4; ++j) {
        float p = exp2a(fmaf(s[i][j][r], 0.06375871f, bp[j * 16]));
        s[i][j][r] = p;
        sum[j] += p;
      }
    }
#pragma unroll
  for (int j = 0; j < 4; ++j) {
    sum[j] += __shfl_xor(sum[j], 16);
    sum[j] += __shfl_xor(sum[j], 32);
    sum[j] = 1.f / sum[j];
  }

  unsigned pk[4][4][2];
#pragma unroll
  for (int j = 0; j < 4; ++j)
#pragma unroll
    for (int i = 0; i < 4; ++i) {
      pk[j][i][0] = pk2(s[i][j][0] * sum[j], s[i][j][1] * sum[j]);
      pk[j][i][1] = pk2(s[i][j][2] * sum[j], s[i][j][3] * sum[j]);
    }

  f32x4 o[4][2] = {};
#pragma unroll
  for (int j = 0; j < 4; ++j) {
    bf16x8 a0 = mk8(pk[j][0][0], pk[j][0][1], pk[j][1][0], pk[j][1][1]);
    bf16x8 a1 = mk8(pk[j][2][0], pk[j][2][1], pk[j][3][0], pk[j][3][1]);
    o[j][0] = MFMA(a0, vf[0][0], o[j][0], 0, 0, 0);
    o[j][0] = MFMA(a1, vf[1][0], o[j][0], 0, 0, 0);
    o[j][1] = MFMA(a0, vf[0][1], o[j][1], 0, 0, 0);
    o[j][1] = MFMA(a1, vf[1][1], o[j][1], 0, 0, 0);
  }

#pragma unroll
  for (int j = 0; j < 4; ++j)
#pragma unroll
    for (int r = 0; r < 4; ++r) {
      int n = j * 16 + g4 + r;
      if (n < 49) {
        long off = ((long)b * 49 + n) * 512 + h * 32 + l15;
        ao[off]      = f2bf(o[j][0][r]);
        ao[off + 16] = f2bf(o[j][1][r]);
      }
    }
}

// ---------------- host ----------------

extern "C" void kernel_launch(void* const* d_in, const int* in_sizes, int n_in,
                              void* d_out, int out_size, void* d_ws, size_t ws_size,
                              hipStream_t stream) {
  (void)in_sizes; (void)n_in; (void)ws_size;
  const float* x      = (const float*)d_in[0];
  const float* w_qkv  = (const float*)d_in[1];
  const float* b_qkv  = (const float*)d_in[2];
  const float* w_proj = (const float*)d_in[3];
  const float* b_proj = (const float*)d_in[4];
  const float* btab   = (const float*)d_in[5];

  char* ws = (char*)d_ws;
  short* wqP = (short*)ws;                                   //   1,572,864 B
  short* wpP = (short*)(ws + 1572864L);                      //     524,288 B
  short* qkv = (short*)(ws + 2097152L);                      // 616,562,688 B
  short* ao  = (short*)(ws + 2097152L + 616562688L);         // 205,520,896 B
  // biasT in d_out tail: written by prep_k, read by attn49, fully overwritten by proj.
  float* biasT = (float*)d_out + (out_size - 65536);

  prep_k<<<4352, 256, 0, stream>>>(w_qkv, w_proj, btab, wqP, wpP, biasT);
  gemm256<0, true><<<4704, 512, 0, stream>>>(x, wqP, b_qkv, (void*)qkv, 6);
  attn49<<<16384, 256, 0, stream>>>(qkv, biasT, ao);
  gemm256<1, false><<<1568, 512, 0, stream>>>(ao, wpP, b_proj, d_out, 2);
}